// Round 6
// baseline (207.625 us; speedup 1.0000x reference)
//
#include <hip/hip_runtime.h>
#include <hip/hip_fp16.h>

// Smoother: out = max(pred, (reflect-pad moving-sum(K=501) + bias)/K)
// pred: [B=8, T=16384, C=128] fp32.
//
// Round 13 (= r12 resubmit after container-infra failure, + fp32 vc):
// r9-r11 post-mortem: three structures all stuck 51-57 us with every pipe
// <=40% => latency*concurrency bound (8-16 waves/CU + serial recurrence).
//  * 1024 blocks x 512 thr; LDS 40960 B/block = exactly 4 blocks/CU ->
//    32 waves/CU. __launch_bounds__(512,8) caps VGPR at 64.
//  * fp16 ring for vn/vo only: window-sum error telescopes (each value
//    enters +vn then -vo identically rounded) -> ~1e-5 after /K.
//  * vc (center/passthrough) read from GLOBAL fp32 -- avoids emitting
//    fp16-rounded pred on the max() passthrough path (2.4e-3 risk).
//    Row t was staged by this block 251 rows ago -> L2-hit; load issued in
//    phase (a), latency hidden under the prefix shuffles.
//  * lane=row layout: wave = 64 rows x its 4 channels; ONE 6-level prefix
//    per 64 rows (28 shuffles vs r11's 128; serial chain 7 vs 32 levels).
//  * ring row = 64 B, slot swizzle (q+p+(p>>3))&7: enumerated -> exactly
//    4 lanes/bank-pair for any 64-row aligned window (b64 floor).
//  * stage schedule: issue loads -> compute -> barrier -> ds_write ->
//    barrier. Each global row staged once (+margins): ~134 MB reads staged
//    + 67 MB vc re-reads (L2) + 67 MB writes.

constexpr int B     = 8;
constexpr int T     = 16384;
constexpr int C     = 128;
constexpr int K     = 501;
constexpr int CHN   = 32;             // channels per block
constexpr int NCG   = C / CHN;        // 4
constexpr int NSEG  = 32;             // segments
constexpr int SEGR  = T / NSEG;       // 512 rows per block
constexpr int STEP  = 64;             // rows per compute step
constexpr int NSTEP = SEGR / STEP;    // 8
constexpr int CHK   = 64;             // staged rows per chunk
constexpr int RROWS = 640;            // ring rows (10 chunks)
constexpr int MARG  = 256;            // rows staged before g0
constexpr int PRO   = 9;              // prologue chunks (rows g0-256..g0+319)
constexpr int NCHK  = 16;             // total chunks  (rows g0-256..g0+767)

__device__ __forceinline__ int ridx(int j) {
    j = (j < 0) ? -j : j;
    return (j >= T) ? (2 * T - 2 - j) : j;
}

typedef float f32x4 __attribute__((ext_vector_type(4)));

__global__ __launch_bounds__(512, 8) void smoother_kernel(
    const float* __restrict__ pred, const float* __restrict__ bias,
    float* __restrict__ out) {
    // ring row p (64 B = 32 ch fp16), slot q holds channels 4q..4q+3.
    // physical slot = (q + p + (p>>3)) & 7  -> uniform bank-pair spread.
    __shared__ __align__(16) unsigned int ring[RROWS * 16];   // 40960 B

    const int b   = blockIdx.x & 7;
    const int cg  = (blockIdx.x >> 3) & (NCG - 1);
    const int seg = blockIdx.x >> 5;
    const int g0  = seg * SEGR;
    const int jstart = g0 - MARG;

    const int tid  = threadIdx.x;
    const int lane = tid & 63;        // row offset within step
    const int w    = tid >> 6;        // wave = channel quad 0..7

    // staging mapping: 512 threads = 64 rows x 8 quads
    const int srow = tid >> 3;
    const int sq   = tid & 7;

    const float* pb = pred + (size_t)b * T * C + cg * CHN;
    float*       ob = out  + (size_t)b * T * C + cg * CHN;

    const float rk  = 1.0f / (float)K;
    const float brk = bias[0] * rk;

    // ---- prologue: stage chunks 0..8 (rows jstart .. jstart+575) ----
    #pragma unroll 3
    for (int m = 0; m < PRO; ++m) {
        const int jr = ridx(jstart + m * CHK + srow);
        const float4 v = *reinterpret_cast<const float4*>(
            pb + (size_t)jr * C + sq * 4);
        const int p = m * CHK + srow;             // < 640, no wrap
        __half2 h0 = __float22half2_rn(make_float2(v.x, v.y));
        __half2 h1 = __float22half2_rn(make_float2(v.z, v.w));
        const int slot = (sq + p + (p >> 3)) & 7;
        unsigned int* d = &ring[p * 16 + slot * 2];
        d[0] = *reinterpret_cast<unsigned int*>(&h0);
        d[1] = *reinterpret_cast<unsigned int*>(&h1);
    }
    __syncthreads();

    // ---- seed: S = sum rows [g0-250, g0+250] = phases 6..506 ----
    float Sx = 0.f, Sy = 0.f, Sz = 0.f, Sw = 0.f;
    {
        #pragma unroll
        for (int k = 0; k < 7; ++k) {
            const int p = 6 + lane + 64 * k;
            const int slot = (w + p + (p >> 3)) & 7;
            const uint2 v = *reinterpret_cast<const uint2*>(
                &ring[p * 16 + slot * 2]);
            const float2 lo = __half22float2(*reinterpret_cast<const __half2*>(&v.x));
            const float2 hi = __half22float2(*reinterpret_cast<const __half2*>(&v.y));
            Sx += lo.x; Sy += lo.y; Sz += hi.x; Sw += hi.y;
        }
        if (lane <= 52) {
            const int p = 454 + lane;
            const int slot = (w + p + (p >> 3)) & 7;
            const uint2 v = *reinterpret_cast<const uint2*>(
                &ring[p * 16 + slot * 2]);
            const float2 lo = __half22float2(*reinterpret_cast<const __half2*>(&v.x));
            const float2 hi = __half22float2(*reinterpret_cast<const __half2*>(&v.y));
            Sx += lo.x; Sy += lo.y; Sz += hi.x; Sw += hi.y;
        }
        #pragma unroll
        for (int d = 1; d <= 32; d <<= 1) {
            Sx += __shfl_xor(Sx, d);
            Sy += __shfl_xor(Sy, d);
            Sz += __shfl_xor(Sz, d);
            Sw += __shfl_xor(Sw, d);
        }
    }

    // ---- slide: 8 iters x 64 rows ----
    #pragma unroll 1
    for (int i = 0; i < NSTEP; ++i) {
        // (a) issue next chunk's stage load + this step's fp32 vc load
        float4 sv;
        int sp = 0;
        const bool do_stage = (PRO + i) < NCHK;   // i <= 6
        if (do_stage) {
            const int m  = PRO + i;
            const int jr = ridx(jstart + m * CHK + srow);
            sv = *reinterpret_cast<const float4*>(pb + (size_t)jr * C + sq * 4);
            sp = m * CHK + srow; if (sp >= RROWS) sp -= RROWS;
        }
        const float4 cv = *reinterpret_cast<const float4*>(
            pb + (size_t)(g0 + 64 * i + lane) * C + w * 4);

        // (b) compute step i from ring: vn (t+251), vo (t-250)
        int pn = 507 + 64 * i + lane; if (pn >= RROWS) pn -= RROWS;
        int po = 6   + 64 * i + lane;                             // < 518
        const int sn = (w + pn + (pn >> 3)) & 7;
        const int so = (w + po + (po >> 3)) & 7;
        const uint2 un = *reinterpret_cast<const uint2*>(&ring[pn * 16 + sn * 2]);
        const uint2 uo = *reinterpret_cast<const uint2*>(&ring[po * 16 + so * 2]);
        const float2 nlo = __half22float2(*reinterpret_cast<const __half2*>(&un.x));
        const float2 nhi = __half22float2(*reinterpret_cast<const __half2*>(&un.y));
        const float2 olo = __half22float2(*reinterpret_cast<const __half2*>(&uo.x));
        const float2 ohi = __half22float2(*reinterpret_cast<const __half2*>(&uo.y));

        const float dx = nlo.x - olo.x;
        const float dy = nlo.y - olo.y;
        const float dz = nhi.x - ohi.x;
        const float dw = nhi.y - ohi.y;

        // inclusive prefix over 64 rows (Hillis-Steele, 6 levels)
        float xx = dx, xy = dy, xz = dz, xw = dw;
        #pragma unroll
        for (int lvl = 0; lvl < 6; ++lvl) {
            const int dd = 1 << lvl;
            const float ux = __shfl_up(xx, dd);
            const float uy = __shfl_up(xy, dd);
            const float uz = __shfl_up(xz, dd);
            const float uw = __shfl_up(xw, dd);
            if (lane >= dd) { xx += ux; xy += uy; xz += uz; xw += uw; }
        }
        const float totx = __shfl(xx, 63);
        const float toty = __shfl(xy, 63);
        const float totz = __shfl(xz, 63);
        const float totw = __shfl(xw, 63);

        f32x4 o;
        o.x = fmaxf(cv.x, fmaf(Sx + (xx - dx), rk, brk));
        o.y = fmaxf(cv.y, fmaf(Sy + (xy - dy), rk, brk));
        o.z = fmaxf(cv.z, fmaf(Sz + (xz - dz), rk, brk));
        o.w = fmaxf(cv.w, fmaf(Sw + (xw - dw), rk, brk));
        __builtin_nontemporal_store(
            o, reinterpret_cast<f32x4*>(ob + (size_t)(g0 + 64 * i + lane) * C + w * 4));

        Sx += totx; Sy += toty; Sz += totz; Sw += totw;

        // (c) all reads of old ring data done
        __syncthreads();

        // (d) write staged chunk into ring
        if (do_stage) {
            __half2 h0 = __float22half2_rn(make_float2(sv.x, sv.y));
            __half2 h1 = __float22half2_rn(make_float2(sv.z, sv.w));
            const int slot = (sq + sp + (sp >> 3)) & 7;
            unsigned int* d = &ring[sp * 16 + slot * 2];
            d[0] = *reinterpret_cast<unsigned int*>(&h0);
            d[1] = *reinterpret_cast<unsigned int*>(&h1);
        }
        // (e) staged data visible before next iter's reads
        __syncthreads();
    }
}

extern "C" void kernel_launch(void* const* d_in, const int* in_sizes, int n_in,
                              void* d_out, int out_size, void* d_ws, size_t ws_size,
                              hipStream_t stream) {
    const float* pred = (const float*)d_in[0];
    const float* bias = (const float*)d_in[1];
    float*       out  = (float*)d_out;

    const int blocks = B * NCG * NSEG;   // 1024
    smoother_kernel<<<blocks, 512, 0, stream>>>(pred, bias, out);
}

// Round 7
// 165.533 us; speedup vs baseline: 1.2543x; 1.2543x over previous
//
#include <hip/hip_runtime.h>

// Smoother: out = max(pred, (reflect-pad moving-sum(K=501) + bias)/K)
// pred: [B=8, T=16384, C=128] fp32.
//
// Round 14: register delay-line + LDS output transpose.
// r13 post-mortem: WRITE_SIZE 219 MB (3.3x ideal) at 1.75 TB/s = saturated
// HBM partial-write RMW path -- lane=row stores put 16 B into 64 different
// lines per instruction. r9/r11 post-mortem: 3-stream global re-reads
// (~340 MB issued) miss L2 (reuse distance x 256 resident blocks >> 4 MB/XCD)
// and stall on L3.
// Fix both at once, keeping the 64-row lane=row COMPUTE layout:
//  * vn (t+251) is the ONLY global read stream. With 64-row steps,
//    vc(t) = vn delayed 4 steps - 5 lanes; vo(t-250) = vn delayed
//    8 steps - 53 lanes. Keep last 9 vn loads in a rotating register
//    history (fully unrolled -> static indices), synthesize vc/vo with
//    2 shuffles + select each. Issued reads: 134 MB (vs r11's ~340 MB).
//  * seed = masked sum of the 8 prologue history registers + 64-lane
//    xor-reduce -- no extra loads.
//  * stores via 18 KB double-buffered LDS transpose (row stride 144 B):
//    store phase maps thread -> (row tid>>3, quad tid&7) so each wave
//    stores 8 FULL 128 B lines per instruction (r11's proven pattern).
//    One barrier per 64-row step (8 total; double buffer makes one enough).
//  * 1024 blocks x 512 thr; LDS 18432 B; launch_bounds(512,6) caps VGPR 85.

constexpr int B     = 8;
constexpr int T     = 16384;
constexpr int C     = 128;
constexpr int K     = 501;
constexpr int CHN   = 32;             // channels per block
constexpr int NCG   = C / CHN;        // 4
constexpr int NSEG  = 32;             // segments
constexpr int SEGR  = T / NSEG;       // 512 rows per block
constexpr int NSTEP = SEGR / 64;      // 8 steps of 64 rows

__device__ __forceinline__ int ridx(int j) {
    j = (j < 0) ? -j : j;
    return (j >= T) ? (2 * T - 2 - j) : j;
}

typedef float f32x4 __attribute__((ext_vector_type(4)));

__global__ __launch_bounds__(512, 6) void smoother_kernel(
    const float* __restrict__ pred, const float* __restrict__ bias,
    float* __restrict__ out) {
    // output transpose buffer: [2][64 rows][36 floats] (32 ch + 4 pad)
    __shared__ __align__(16) float obuf[2][64][36];   // 18432 B

    const int b   = blockIdx.x & 7;
    const int cg  = (blockIdx.x >> 3) & (NCG - 1);
    const int seg = blockIdx.x >> 5;
    const int g0  = seg * SEGR;

    const int tid  = threadIdx.x;
    const int lane = tid & 63;        // row within step (compute phase)
    const int w    = tid >> 6;        // wave = channel quad 0..7

    const int srow = tid >> 3;        // row within step (store phase)
    const int sq   = tid & 7;         // channel quad (store phase)

    const float* pb = pred + (size_t)b * T * C + cg * CHN;
    float*       ob = out  + (size_t)b * T * C + cg * CHN;

    const float rk  = 1.0f / (float)K;
    const float brk = bias[0] * rk;

    // rows touched: [g0-261, g0+762]
    const bool interior = (seg >= 1) && (seg <= NSEG - 2);

    // ---- prologue: history Rh[m] = R(m-8), R(j) = rows g0+64j+251+lane ----
    float4 Rh[17];
    if (interior) {
        #pragma unroll
        for (int m = 0; m < 9; ++m) {
            const int r = g0 + 64 * (m - 8) + 251 + lane;
            Rh[m] = *reinterpret_cast<const float4*>(pb + (size_t)r * C + w * 4);
        }
    } else {
        #pragma unroll
        for (int m = 0; m < 9; ++m) {
            const int r = ridx(g0 + 64 * (m - 8) + 251 + lane);
            Rh[m] = *reinterpret_cast<const float4*>(pb + (size_t)r * C + w * 4);
        }
    }

    // ---- seed: S = sum rows [g0-250, g0+250] ----
    // Rh[0] rows g0-261+lane: include lanes >= 11; Rh[1..7] all included.
    float4 acc = make_float4(0.f, 0.f, 0.f, 0.f);
    #pragma unroll
    for (int m = 1; m < 8; ++m) {
        acc.x += Rh[m].x; acc.y += Rh[m].y; acc.z += Rh[m].z; acc.w += Rh[m].w;
    }
    if (lane >= 11) {
        acc.x += Rh[0].x; acc.y += Rh[0].y; acc.z += Rh[0].z; acc.w += Rh[0].w;
    }
    #pragma unroll
    for (int dd = 1; dd <= 32; dd <<= 1) {
        acc.x += __shfl_xor(acc.x, dd);
        acc.y += __shfl_xor(acc.y, dd);
        acc.z += __shfl_xor(acc.z, dd);
        acc.w += __shfl_xor(acc.w, dd);
    }
    float4 S = acc;                   // window sum at row g0, per channel

    // ---- 8 steps x 64 rows ----
    #pragma unroll
    for (int i = 0; i < NSTEP; ++i) {
        // issue next history load early (hidden under the shuffle chain)
        if (i < NSTEP - 1) {
            const int r0 = g0 + 64 * (i + 1) + 251 + lane;
            const int r  = interior ? r0 : ridx(r0);
            Rh[9 + i] = *reinterpret_cast<const float4*>(pb + (size_t)r * C + w * 4);
        }

        const float4 vn = Rh[8 + i];                 // rows t+251
        const float4 Av = Rh[4 + i], Bv = Rh[5 + i]; // vc sources
        const float4 Ao = Rh[i],     Bo = Rh[1 + i]; // vo sources

        // vc(t): lanes 0..58 <- Av[lane+5]; lanes 59..63 <- Bv[lane-59]
        // vo(t-250): lanes 0..52 <- Ao[lane+11]; lanes 53..63 <- Bo[lane-53]
        const int sc0 = lane + 5,  sc1 = lane - 59;
        const int so0 = lane + 11, so1 = lane - 53;
        float4 vc, vo;
        {
            float a0, a1;
            a0 = __shfl(Av.x, sc0); a1 = __shfl(Bv.x, sc1); vc.x = (lane <= 58) ? a0 : a1;
            a0 = __shfl(Av.y, sc0); a1 = __shfl(Bv.y, sc1); vc.y = (lane <= 58) ? a0 : a1;
            a0 = __shfl(Av.z, sc0); a1 = __shfl(Bv.z, sc1); vc.z = (lane <= 58) ? a0 : a1;
            a0 = __shfl(Av.w, sc0); a1 = __shfl(Bv.w, sc1); vc.w = (lane <= 58) ? a0 : a1;
            a0 = __shfl(Ao.x, so0); a1 = __shfl(Bo.x, so1); vo.x = (lane <= 52) ? a0 : a1;
            a0 = __shfl(Ao.y, so0); a1 = __shfl(Bo.y, so1); vo.y = (lane <= 52) ? a0 : a1;
            a0 = __shfl(Ao.z, so0); a1 = __shfl(Bo.z, so1); vo.z = (lane <= 52) ? a0 : a1;
            a0 = __shfl(Ao.w, so0); a1 = __shfl(Bo.w, so1); vo.w = (lane <= 52) ? a0 : a1;
        }

        const float dx = vn.x - vo.x;
        const float dy = vn.y - vo.y;
        const float dz = vn.z - vo.z;
        const float dw = vn.w - vo.w;

        // inclusive prefix over 64 rows (Hillis-Steele, 6 levels)
        float xx = dx, xy = dy, xz = dz, xw = dw;
        #pragma unroll
        for (int lvl = 0; lvl < 6; ++lvl) {
            const int dd = 1 << lvl;
            const float ux = __shfl_up(xx, dd);
            const float uy = __shfl_up(xy, dd);
            const float uz = __shfl_up(xz, dd);
            const float uw = __shfl_up(xw, dd);
            if (lane >= dd) { xx += ux; xy += uy; xz += uz; xw += uw; }
        }

        float4 o;
        o.x = fmaxf(vc.x, fmaf(S.x + (xx - dx), rk, brk));
        o.y = fmaxf(vc.y, fmaf(S.y + (xy - dy), rk, brk));
        o.z = fmaxf(vc.z, fmaf(S.z + (xz - dz), rk, brk));
        o.w = fmaxf(vc.w, fmaf(S.w + (xw - dw), rk, brk));

        S.x += __shfl(xx, 63);
        S.y += __shfl(xy, 63);
        S.z += __shfl(xz, 63);
        S.w += __shfl(xw, 63);

        // transpose through LDS: compute layout (row=lane, quad=w) ->
        // store layout (row=tid>>3, quad=tid&7) = full 128 B lines per wave
        *reinterpret_cast<float4*>(&obuf[i & 1][lane][w * 4]) = o;
        __syncthreads();
        const float4 ov = *reinterpret_cast<const float4*>(&obuf[i & 1][srow][sq * 4]);
        __builtin_nontemporal_store(
            *reinterpret_cast<const f32x4*>(&ov),
            reinterpret_cast<f32x4*>(ob + (size_t)(g0 + 64 * i + srow) * C + sq * 4));
    }
}

extern "C" void kernel_launch(void* const* d_in, const int* in_sizes, int n_in,
                              void* d_out, int out_size, void* d_ws, size_t ws_size,
                              hipStream_t stream) {
    const float* pred = (const float*)d_in[0];
    const float* bias = (const float*)d_in[1];
    float*       out  = (float*)d_out;

    const int blocks = B * NCG * NSEG;   // 1024
    smoother_kernel<<<blocks, 512, 0, stream>>>(pred, bias, out);
}

// Round 8
// 162.477 us; speedup vs baseline: 1.2779x; 1.0188x over previous
//
#include <hip/hip_runtime.h>

// Smoother: out = max(pred, (reflect-pad moving-sum(K=501) + bias)/K)
// pred: [B=8, T=16384, C=128] fp32.
//
// Round 15: register delay-line, zero LDS, zero barriers, cached stores.
// r14 post-mortem: traffic was near-ideal (FETCH 58 MB, WRITE 82 MB) yet
// 80 us with every pipe idle. Suspects: (a) VGPR_Count=40 under
// launch_bounds(512,6)'s 85-reg cap => the 9-deep float4 history was
// forced into AGPR/scratch round-trips (WRITE +16 MB = exactly 32 B/thread
// spilled); (b) per-step __syncthreads + nt-store lockstep. This round
// keeps the proven delay-line math (r14 passed, absmax 4.9e-4) and strips
// the packaging:
//  * launch_bounds(512,2): 128-VGPR budget -> history lives in VGPRs.
//  * NO LDS transpose, NO barriers: stores stay in lane=row layout as
//    PLAIN CACHED stores (no nontemporal). The 8 waves of a block write
//    the 8 x 16 B pieces of each 128 B line in the same step on the same
//    XCD L2 within ~1 us << line lifetime -> L2 byte-mask merge gives
//    full-line HBM writebacks. (r13's 219 MB came from nt = stream/evict
//    partial lines immediately.) WRITE_SIZE adjudicates.
//  * vn (t+251) is the only global read stream: vc(t) = 2-shuffle synth
//    from history (4 steps - 5 lanes), vo(t-250) = 2-shuffle synth
//    (8 steps - 53 lanes); seed = masked sum of prologue registers.
// Issued bytes: 134 MB reads + 66 MB writes = 200 MB -> ~32 us at the
// 6.3 TB/s issue ceiling; shuffles ride the parallel LDS pipe (shadowed).

constexpr int B     = 8;
constexpr int T     = 16384;
constexpr int C     = 128;
constexpr int K     = 501;
constexpr int CHN   = 32;             // channels per block
constexpr int NCG   = C / CHN;        // 4
constexpr int NSEG  = 32;             // segments
constexpr int SEGR  = T / NSEG;       // 512 rows per block
constexpr int NSTEP = SEGR / 64;      // 8 steps of 64 rows

__device__ __forceinline__ int ridx(int j) {
    j = (j < 0) ? -j : j;
    return (j >= T) ? (2 * T - 2 - j) : j;
}

__global__ __launch_bounds__(512, 2) void smoother_kernel(
    const float* __restrict__ pred, const float* __restrict__ bias,
    float* __restrict__ out) {
    const int b   = blockIdx.x & 7;
    const int cg  = (blockIdx.x >> 3) & (NCG - 1);
    const int seg = blockIdx.x >> 5;
    const int g0  = seg * SEGR;

    const int tid  = threadIdx.x;
    const int lane = tid & 63;        // row within step
    const int w    = tid >> 6;        // wave = channel quad 0..7

    const float* pb = pred + (size_t)b * T * C + cg * CHN;
    float*       ob = out  + (size_t)b * T * C + cg * CHN;

    const float rk  = 1.0f / (float)K;
    const float brk = bias[0] * rk;

    // rows touched: [g0-261, g0+762]
    const bool interior = (seg >= 1) && (seg <= NSEG - 2);

    // ---- prologue: history Rh[m] = R(m-8), R(j) = rows g0+64j+251+lane ----
    float4 Rh[17];
    if (interior) {
        #pragma unroll
        for (int m = 0; m < 9; ++m) {
            const int r = g0 + 64 * (m - 8) + 251 + lane;
            Rh[m] = *reinterpret_cast<const float4*>(pb + (size_t)r * C + w * 4);
        }
    } else {
        #pragma unroll
        for (int m = 0; m < 9; ++m) {
            const int r = ridx(g0 + 64 * (m - 8) + 251 + lane);
            Rh[m] = *reinterpret_cast<const float4*>(pb + (size_t)r * C + w * 4);
        }
    }

    // ---- seed: S = sum rows [g0-250, g0+250] ----
    // Rh[0] = rows g0-261+lane: include lanes >= 11; Rh[1..7] all included.
    float4 acc = make_float4(0.f, 0.f, 0.f, 0.f);
    #pragma unroll
    for (int m = 1; m < 8; ++m) {
        acc.x += Rh[m].x; acc.y += Rh[m].y; acc.z += Rh[m].z; acc.w += Rh[m].w;
    }
    if (lane >= 11) {
        acc.x += Rh[0].x; acc.y += Rh[0].y; acc.z += Rh[0].z; acc.w += Rh[0].w;
    }
    #pragma unroll
    for (int dd = 1; dd <= 32; dd <<= 1) {
        acc.x += __shfl_xor(acc.x, dd);
        acc.y += __shfl_xor(acc.y, dd);
        acc.z += __shfl_xor(acc.z, dd);
        acc.w += __shfl_xor(acc.w, dd);
    }
    float4 S = acc;                   // window sum at row g0, per channel

    // ---- 8 steps x 64 rows, no barriers ----
    #pragma unroll
    for (int i = 0; i < NSTEP; ++i) {
        // issue next history load early (hidden under the shuffle chain)
        if (i < NSTEP - 1) {
            const int r0 = g0 + 64 * (i + 1) + 251 + lane;
            const int r  = interior ? r0 : ridx(r0);
            Rh[9 + i] = *reinterpret_cast<const float4*>(pb + (size_t)r * C + w * 4);
        }

        const float4 vn = Rh[8 + i];                 // rows t+251
        const float4 Av = Rh[4 + i], Bv = Rh[5 + i]; // vc sources
        const float4 Ao = Rh[i],     Bo = Rh[1 + i]; // vo sources

        // vc(t): lanes 0..58 <- Av[lane+5]; lanes 59..63 <- Bv[lane-59]
        // vo(t-250): lanes 0..52 <- Ao[lane+11]; lanes 53..63 <- Bo[lane-53]
        const int sc0 = lane + 5,  sc1 = lane - 59;
        const int so0 = lane + 11, so1 = lane - 53;
        float4 vc, vo;
        {
            float a0, a1;
            a0 = __shfl(Av.x, sc0); a1 = __shfl(Bv.x, sc1); vc.x = (lane <= 58) ? a0 : a1;
            a0 = __shfl(Av.y, sc0); a1 = __shfl(Bv.y, sc1); vc.y = (lane <= 58) ? a0 : a1;
            a0 = __shfl(Av.z, sc0); a1 = __shfl(Bv.z, sc1); vc.z = (lane <= 58) ? a0 : a1;
            a0 = __shfl(Av.w, sc0); a1 = __shfl(Bv.w, sc1); vc.w = (lane <= 58) ? a0 : a1;
            a0 = __shfl(Ao.x, so0); a1 = __shfl(Bo.x, so1); vo.x = (lane <= 52) ? a0 : a1;
            a0 = __shfl(Ao.y, so0); a1 = __shfl(Bo.y, so1); vo.y = (lane <= 52) ? a0 : a1;
            a0 = __shfl(Ao.z, so0); a1 = __shfl(Bo.z, so1); vo.z = (lane <= 52) ? a0 : a1;
            a0 = __shfl(Ao.w, so0); a1 = __shfl(Bo.w, so1); vo.w = (lane <= 52) ? a0 : a1;
        }

        const float dx = vn.x - vo.x;
        const float dy = vn.y - vo.y;
        const float dz = vn.z - vo.z;
        const float dw = vn.w - vo.w;

        // inclusive prefix over 64 rows (Hillis-Steele, 6 levels)
        float xx = dx, xy = dy, xz = dz, xw = dw;
        #pragma unroll
        for (int lvl = 0; lvl < 6; ++lvl) {
            const int dd = 1 << lvl;
            const float ux = __shfl_up(xx, dd);
            const float uy = __shfl_up(xy, dd);
            const float uz = __shfl_up(xz, dd);
            const float uw = __shfl_up(xw, dd);
            if (lane >= dd) { xx += ux; xy += uy; xz += uz; xw += uw; }
        }

        float4 o;
        o.x = fmaxf(vc.x, fmaf(S.x + (xx - dx), rk, brk));
        o.y = fmaxf(vc.y, fmaf(S.y + (xy - dy), rk, brk));
        o.z = fmaxf(vc.z, fmaf(S.z + (xz - dz), rk, brk));
        o.w = fmaxf(vc.w, fmaf(S.w + (xw - dw), rk, brk));

        S.x += __shfl(xx, 63);
        S.y += __shfl(xy, 63);
        S.z += __shfl(xz, 63);
        S.w += __shfl(xw, 63);

        // lane=row cached store: 16 B piece; the block's 8 waves cover the
        // full 128 B line in the same step -> L2 byte-mask merge.
        *reinterpret_cast<float4*>(
            ob + (size_t)(g0 + 64 * i + lane) * C + w * 4) = o;
    }
}

extern "C" void kernel_launch(void* const* d_in, const int* in_sizes, int n_in,
                              void* d_out, int out_size, void* d_ws, size_t ws_size,
                              hipStream_t stream) {
    const float* pred = (const float*)d_in[0];
    const float* bias = (const float*)d_in[1];
    float*       out  = (float*)d_out;

    const int blocks = B * NCG * NSEG;   // 1024
    smoother_kernel<<<blocks, 512, 0, stream>>>(pred, bias, out);
}

// Round 9
// 156.423 us; speedup vs baseline: 1.3273x; 1.0387x over previous
//
#include <hip/hip_runtime.h>

// Smoother: out = max(pred, (reflect-pad moving-sum(K=501) + bias)/K)
// pred: [B=8, T=16384, C=128] fp32.
//
// Round 16: delay-line with STATIC registers + DPP scan + merged bpermute.
// r15 post-mortem: VGPR_Count=44 (< the 68 regs the 17-float4 history
// needs) + WRITE_SIZE 91 MB (66 ideal + ~25 MB = 512thr x 48 B/thread)
// => the runtime-indexed Rh[8+i] array lived in SCRATCH (rule: runtime-
// indexed arrays -> private memory), every step round-tripping history
// through global-backed scratch. Also ~380 ds_bpermute/wave (every __shfl
// is an LDS-pipe op) ~= 29 us/CU of hidden LDS-pipe serialization.
// Fixes, keeping the twice-verified delay-line math:
//  * 8 steps fully hand-unrolled over NAMED registers R0..R15 -- no
//    runtime indexing anywhere, scratch impossible. VGPR_Count ~100
//    expected (the adjudicator).
//  * 64-lane inclusive scan via canonical GCN DPP sequence
//    (row_shr:1/2/4/8 + row_bcast:15/31): 6 VALU ops/component on the
//    VALU pipe, zero LDS-pipe.
//  * vc/vo synth: vc[l]=Av[l+5](l<=58)/Bv[l-59](l>=59) == bpermute of
//    M=(lane<5?Bv:Av) at index (l+5)&63 -- 1 cndmask + 1 bpermute per
//    component (8 bpermute/step vs r15's 44 LDS-pipe ops).
//  * S is wave-uniform: step total via v_readlane(x,63), no shuffle.
//  * no LDS buffer, no barriers, plain cached float4 stores (r15's
//    WRITE excess now attributed to spill, not store merge failure).

constexpr int B     = 8;
constexpr int T     = 16384;
constexpr int C     = 128;
constexpr int K     = 501;
constexpr int CHN   = 32;             // channels per block
constexpr int NCG   = C / CHN;        // 4
constexpr int NSEG  = 32;             // segments
constexpr int SEGR  = T / NSEG;       // 512 rows per block

__device__ __forceinline__ int ridx(int j) {
    j = (j < 0) ? -j : j;
    return (j >= T) ? (2 * T - 2 - j) : j;
}

// 64-lane inclusive scan, all on the VALU pipe (DPP), zero LDS-pipe ops.
__device__ __forceinline__ float scan64(float x) {
    x += __int_as_float(__builtin_amdgcn_update_dpp(
        0, __float_as_int(x), 0x111, 0xf, 0xf, true));   // row_shr:1
    x += __int_as_float(__builtin_amdgcn_update_dpp(
        0, __float_as_int(x), 0x112, 0xf, 0xf, true));   // row_shr:2
    x += __int_as_float(__builtin_amdgcn_update_dpp(
        0, __float_as_int(x), 0x114, 0xf, 0xf, true));   // row_shr:4
    x += __int_as_float(__builtin_amdgcn_update_dpp(
        0, __float_as_int(x), 0x118, 0xf, 0xf, true));   // row_shr:8
    x += __int_as_float(__builtin_amdgcn_update_dpp(
        0, __float_as_int(x), 0x142, 0xa, 0xf, false));  // row_bcast:15
    x += __int_as_float(__builtin_amdgcn_update_dpp(
        0, __float_as_int(x), 0x143, 0xc, 0xf, false));  // row_bcast:31
    return x;
}

__device__ __forceinline__ float bperm(int bidx, float v) {
    return __int_as_float(__builtin_amdgcn_ds_bpermute(bidx, __float_as_int(v)));
}
__device__ __forceinline__ float rl63(float x) {
    return __int_as_float(__builtin_amdgcn_readlane(__float_as_int(x), 63));
}

__global__ __launch_bounds__(512, 2) void smoother_kernel(
    const float* __restrict__ pred, const float* __restrict__ bias,
    float* __restrict__ out) {
    const int b   = blockIdx.x & 7;
    const int cg  = (blockIdx.x >> 3) & (NCG - 1);
    const int seg = blockIdx.x >> 5;
    const int g0  = seg * SEGR;

    const int tid  = threadIdx.x;
    const int lane = tid & 63;        // row within step
    const int w    = tid >> 6;        // wave = channel quad 0..7

    const float* pb = pred + (size_t)b * T * C + cg * CHN;
    float*       ob = out  + (size_t)b * T * C + cg * CHN;

    const float rk  = 1.0f / (float)K;
    const float brk = bias[0] * rk;

    // rows touched: [g0-261, g0+762]
    const bool interior = (seg >= 1) && (seg <= NSEG - 2);

    const bool m5  = (lane < 5);
    const bool m11 = (lane < 11);
    const int vcidx = ((lane + 5)  & 63) << 2;   // bpermute byte index
    const int voidx = ((lane + 11) & 63) << 2;

    // R_m holds rows g0 + 64*m - 261 + lane  (the t+251 stream, 8 steps deep)
    float4 R0, R1, R2, R3, R4, R5, R6, R7, R8, R9, R10, R11, R12, R13, R14, R15;

#define LOADR(Rm, m) do {                                                   \
        const int r0_ = g0 + 64 * (m) - 261 + lane;                         \
        const int r_  = interior ? r0_ : ridx(r0_);                         \
        Rm = *reinterpret_cast<const float4*>(pb + (size_t)r_ * C + w * 4); \
    } while (0)

    // ---- prologue: R0..R8 ----
    LOADR(R0, 0); LOADR(R1, 1); LOADR(R2, 2); LOADR(R3, 3); LOADR(R4, 4);
    LOADR(R5, 5); LOADR(R6, 6); LOADR(R7, 7); LOADR(R8, 8);

    // ---- seed: S = sum rows [g0-250, g0+250] ----
    // R1..R7 fully inside; R0 rows g0-261+lane -> include lanes >= 11.
    float4 S;
    {
        float ax = R1.x + R2.x + R3.x + R4.x + R5.x + R6.x + R7.x;
        float ay = R1.y + R2.y + R3.y + R4.y + R5.y + R6.y + R7.y;
        float az = R1.z + R2.z + R3.z + R4.z + R5.z + R6.z + R7.z;
        float aw = R1.w + R2.w + R3.w + R4.w + R5.w + R6.w + R7.w;
        if (lane >= 11) { ax += R0.x; ay += R0.y; az += R0.z; aw += R0.w; }
        #pragma unroll
        for (int dd = 1; dd <= 32; dd <<= 1) {
            ax += __shfl_xor(ax, dd);
            ay += __shfl_xor(ay, dd);
            az += __shfl_xor(az, dd);
            aw += __shfl_xor(aw, dd);
        }
        S.x = ax; S.y = ay; S.z = az; S.w = aw;
    }

    // step i: Ao=R[i], Bo=R[i+1], Av=R[i+4], Bv=R[i+5], Vn=R[i+8]
#define STEP(i, RAo, RBo, RAv, RBv, RVn) do {                               \
        float4 vo_, vc_, d_, x_;                                            \
        vo_.x = bperm(voidx, m11 ? RBo.x : RAo.x);                          \
        vo_.y = bperm(voidx, m11 ? RBo.y : RAo.y);                          \
        vo_.z = bperm(voidx, m11 ? RBo.z : RAo.z);                          \
        vo_.w = bperm(voidx, m11 ? RBo.w : RAo.w);                          \
        vc_.x = bperm(vcidx, m5 ? RBv.x : RAv.x);                           \
        vc_.y = bperm(vcidx, m5 ? RBv.y : RAv.y);                           \
        vc_.z = bperm(vcidx, m5 ? RBv.z : RAv.z);                           \
        vc_.w = bperm(vcidx, m5 ? RBv.w : RAv.w);                           \
        d_.x = RVn.x - vo_.x; d_.y = RVn.y - vo_.y;                         \
        d_.z = RVn.z - vo_.z; d_.w = RVn.w - vo_.w;                         \
        x_.x = scan64(d_.x);  x_.y = scan64(d_.y);                          \
        x_.z = scan64(d_.z);  x_.w = scan64(d_.w);                          \
        float4 o_;                                                          \
        o_.x = fmaxf(vc_.x, fmaf(S.x + (x_.x - d_.x), rk, brk));            \
        o_.y = fmaxf(vc_.y, fmaf(S.y + (x_.y - d_.y), rk, brk));            \
        o_.z = fmaxf(vc_.z, fmaf(S.z + (x_.z - d_.z), rk, brk));            \
        o_.w = fmaxf(vc_.w, fmaf(S.w + (x_.w - d_.w), rk, brk));            \
        *reinterpret_cast<float4*>(                                         \
            ob + (size_t)(g0 + 64 * (i) + lane) * C + w * 4) = o_;          \
        S.x += rl63(x_.x); S.y += rl63(x_.y);                               \
        S.z += rl63(x_.z); S.w += rl63(x_.w);                               \
    } while (0)

    LOADR(R9,  9);  STEP(0, R0, R1, R4,  R5,  R8);
    LOADR(R10, 10); STEP(1, R1, R2, R5,  R6,  R9);
    LOADR(R11, 11); STEP(2, R2, R3, R6,  R7,  R10);
    LOADR(R12, 12); STEP(3, R3, R4, R7,  R8,  R11);
    LOADR(R13, 13); STEP(4, R4, R5, R8,  R9,  R12);
    LOADR(R14, 14); STEP(5, R5, R6, R9,  R10, R13);
    LOADR(R15, 15); STEP(6, R6, R7, R10, R11, R14);
                    STEP(7, R7, R8, R11, R12, R15);

#undef STEP
#undef LOADR
}

extern "C" void kernel_launch(void* const* d_in, const int* in_sizes, int n_in,
                              void* d_out, int out_size, void* d_ws, size_t ws_size,
                              hipStream_t stream) {
    const float* pred = (const float*)d_in[0];
    const float* bias = (const float*)d_in[1];
    float*       out  = (float*)d_out;

    const int blocks = B * NCG * NSEG;   // 1024
    smoother_kernel<<<blocks, 512, 0, stream>>>(pred, bias, out);
}

// Round 10
// 128.587 us; speedup vs baseline: 1.6147x; 1.2165x over previous
//
#include <hip/hip_runtime.h>

// Smoother: out = max(pred, (reflect-pad moving-sum(K=501) + bias)/K)
// pred: [B=8, T=16384, C=128] fp32.
//
// Round 17: delay-line with PINNED 16-deep load burst.
// r16 post-mortem: VGPR_Count=32 (< the 64 regs 16 live float4 need) =>
// the compiler SANK each history load to just before its first use, so
// steady state had ~1 load in flight/wave. Little's law across r9-r16:
// every kernel sat at achieved-BW = in-flight-bytes/latency (~3 KB/wave
// x ~1100 waves / 600 ns ~= 6 TB/s). We never raised in-flight.
// Fixes:
//  * ALL 16 history loads issued up front (16 KB/wave in flight), then
//    __builtin_amdgcn_sched_barrier(0) -- scheduler cannot sink them.
//    STEP(i) waits on a natural vmcnt ladder (load i+8 only).
//  * launch_bounds(512,2): 256-reg budget, no forced spill; expected
//    natural use ~110 -> 2 blocks/CU, 2 pipelined generations.
//  * seed reduce on the VALU pipe: DPP scan64 + readlane(63) (was 24
//    LDS-pipe shfl_xor).
//  * store via r14's LDS transpose (proved WRITE 82 vs 92 MB) + nt
//    full-line stores; double buffer, 1 barrier/step (race-free: waves
//    are never >1 sync apart).
//  * STEP math identical to r16 (passed, absmax 4.9e-4): bperm synth of
//    vc (4 steps - 5 lanes) / vo (8 steps - 53 lanes), DPP scan.
// Also adjudicates the inherited "per-CU ~10 B/cy load-return cap":
// 201 MB issued => ~33 us if the cap is real, ~25 us if it was latency.

constexpr int B     = 8;
constexpr int T     = 16384;
constexpr int C     = 128;
constexpr int K     = 501;
constexpr int CHN   = 32;             // channels per block
constexpr int NCG   = C / CHN;        // 4
constexpr int NSEG  = 32;             // segments
constexpr int SEGR  = T / NSEG;       // 512 rows per block

__device__ __forceinline__ int ridx(int j) {
    j = (j < 0) ? -j : j;
    return (j >= T) ? (2 * T - 2 - j) : j;
}

typedef float f32x4 __attribute__((ext_vector_type(4)));

// 64-lane inclusive scan, all on the VALU pipe (DPP), zero LDS-pipe ops.
__device__ __forceinline__ float scan64(float x) {
    x += __int_as_float(__builtin_amdgcn_update_dpp(
        0, __float_as_int(x), 0x111, 0xf, 0xf, true));   // row_shr:1
    x += __int_as_float(__builtin_amdgcn_update_dpp(
        0, __float_as_int(x), 0x112, 0xf, 0xf, true));   // row_shr:2
    x += __int_as_float(__builtin_amdgcn_update_dpp(
        0, __float_as_int(x), 0x114, 0xf, 0xf, true));   // row_shr:4
    x += __int_as_float(__builtin_amdgcn_update_dpp(
        0, __float_as_int(x), 0x118, 0xf, 0xf, true));   // row_shr:8
    x += __int_as_float(__builtin_amdgcn_update_dpp(
        0, __float_as_int(x), 0x142, 0xa, 0xf, false));  // row_bcast:15
    x += __int_as_float(__builtin_amdgcn_update_dpp(
        0, __float_as_int(x), 0x143, 0xc, 0xf, false));  // row_bcast:31
    return x;
}

__device__ __forceinline__ float bperm(int bidx, float v) {
    return __int_as_float(__builtin_amdgcn_ds_bpermute(bidx, __float_as_int(v)));
}
__device__ __forceinline__ float rl63(float x) {
    return __int_as_float(__builtin_amdgcn_readlane(__float_as_int(x), 63));
}

__global__ __launch_bounds__(512, 2) void smoother_kernel(
    const float* __restrict__ pred, const float* __restrict__ bias,
    float* __restrict__ out) {
    // output transpose buffer: [2][64 rows][36 floats] (32 ch + 4 pad)
    __shared__ __align__(16) float obuf[2][64][36];   // 18432 B

    const int b   = blockIdx.x & 7;
    const int cg  = (blockIdx.x >> 3) & (NCG - 1);
    const int seg = blockIdx.x >> 5;
    const int g0  = seg * SEGR;

    const int tid  = threadIdx.x;
    const int lane = tid & 63;        // row within step (compute phase)
    const int w    = tid >> 6;        // wave = channel quad 0..7

    const int srow = tid >> 3;        // row within step (store phase)
    const int sq   = tid & 7;         // channel quad (store phase)

    const float* pb = pred + (size_t)b * T * C + cg * CHN;
    float*       ob = out  + (size_t)b * T * C + cg * CHN;

    const float rk  = 1.0f / (float)K;
    const float brk = bias[0] * rk;

    // rows touched: [g0-261, g0+762]
    const bool interior = (seg >= 1) && (seg <= NSEG - 2);

    const bool m5  = (lane < 5);
    const bool m11 = (lane < 11);
    const int vcidx = ((lane + 5)  & 63) << 2;   // bpermute byte index
    const int voidx = ((lane + 11) & 63) << 2;

    // R_m holds rows g0 + 64*m - 261 + lane  (the t+251 stream)
    float4 R0, R1, R2, R3, R4, R5, R6, R7, R8, R9, R10, R11, R12, R13, R14, R15;

#define LOADR(Rm, m) do {                                                   \
        const int r0_ = g0 + 64 * (m) - 261 + lane;                         \
        const int r_  = interior ? r0_ : ridx(r0_);                         \
        Rm = *reinterpret_cast<const float4*>(pb + (size_t)r_ * C + w * 4); \
    } while (0)

    // ---- issue the ENTIRE 16-deep history burst, then pin it ----
    LOADR(R0,  0);  LOADR(R1,  1);  LOADR(R2,  2);  LOADR(R3,  3);
    LOADR(R4,  4);  LOADR(R5,  5);  LOADR(R6,  6);  LOADR(R7,  7);
    LOADR(R8,  8);  LOADR(R9,  9);  LOADR(R10, 10); LOADR(R11, 11);
    LOADR(R12, 12); LOADR(R13, 13); LOADR(R14, 14); LOADR(R15, 15);
    __builtin_amdgcn_sched_barrier(0);   // nothing moves across this line

    // ---- seed: S = sum rows [g0-250, g0+250] ----
    // R1..R7 fully inside; R0 rows g0-261+lane -> include lanes >= 11.
    float4 S;
    {
        float ax = R1.x + R2.x + R3.x + R4.x + R5.x + R6.x + R7.x;
        float ay = R1.y + R2.y + R3.y + R4.y + R5.y + R6.y + R7.y;
        float az = R1.z + R2.z + R3.z + R4.z + R5.z + R6.z + R7.z;
        float aw = R1.w + R2.w + R3.w + R4.w + R5.w + R6.w + R7.w;
        if (lane >= 11) { ax += R0.x; ay += R0.y; az += R0.z; aw += R0.w; }
        S.x = rl63(scan64(ax));
        S.y = rl63(scan64(ay));
        S.z = rl63(scan64(az));
        S.w = rl63(scan64(aw));
    }

    // step i: Ao=R[i], Bo=R[i+1], Av=R[i+4], Bv=R[i+5], Vn=R[i+8]
#define STEP(i, RAo, RBo, RAv, RBv, RVn) do {                               \
        float4 vo_, vc_, d_, x_;                                            \
        vo_.x = bperm(voidx, m11 ? RBo.x : RAo.x);                          \
        vo_.y = bperm(voidx, m11 ? RBo.y : RAo.y);                          \
        vo_.z = bperm(voidx, m11 ? RBo.z : RAo.z);                          \
        vo_.w = bperm(voidx, m11 ? RBo.w : RAo.w);                          \
        vc_.x = bperm(vcidx, m5 ? RBv.x : RAv.x);                           \
        vc_.y = bperm(vcidx, m5 ? RBv.y : RAv.y);                           \
        vc_.z = bperm(vcidx, m5 ? RBv.z : RAv.z);                           \
        vc_.w = bperm(vcidx, m5 ? RBv.w : RAv.w);                           \
        d_.x = RVn.x - vo_.x; d_.y = RVn.y - vo_.y;                         \
        d_.z = RVn.z - vo_.z; d_.w = RVn.w - vo_.w;                         \
        x_.x = scan64(d_.x);  x_.y = scan64(d_.y);                          \
        x_.z = scan64(d_.z);  x_.w = scan64(d_.w);                          \
        float4 o_;                                                          \
        o_.x = fmaxf(vc_.x, fmaf(S.x + (x_.x - d_.x), rk, brk));            \
        o_.y = fmaxf(vc_.y, fmaf(S.y + (x_.y - d_.y), rk, brk));            \
        o_.z = fmaxf(vc_.z, fmaf(S.z + (x_.z - d_.z), rk, brk));            \
        o_.w = fmaxf(vc_.w, fmaf(S.w + (x_.w - d_.w), rk, brk));            \
        S.x += rl63(x_.x); S.y += rl63(x_.y);                               \
        S.z += rl63(x_.z); S.w += rl63(x_.w);                               \
        /* transpose: compute layout (row=lane, quad=w) ->                */\
        /* store layout (row=tid>>3, quad=tid&7) = full 128 B lines      */\
        *reinterpret_cast<float4*>(&obuf[(i) & 1][lane][w * 4]) = o_;       \
        __syncthreads();                                                    \
        const float4 ov_ = *reinterpret_cast<const float4*>(                \
            &obuf[(i) & 1][srow][sq * 4]);                                  \
        __builtin_nontemporal_store(                                        \
            *reinterpret_cast<const f32x4*>(&ov_),                          \
            reinterpret_cast<f32x4*>(                                       \
                ob + (size_t)(g0 + 64 * (i) + srow) * C + sq * 4));         \
    } while (0)

    STEP(0, R0, R1, R4,  R5,  R8);
    STEP(1, R1, R2, R5,  R6,  R9);
    STEP(2, R2, R3, R6,  R7,  R10);
    STEP(3, R3, R4, R7,  R8,  R11);
    STEP(4, R4, R5, R8,  R9,  R12);
    STEP(5, R5, R6, R9,  R10, R13);
    STEP(6, R6, R7, R10, R11, R14);
    STEP(7, R7, R8, R11, R12, R15);

#undef STEP
#undef LOADR
}

extern "C" void kernel_launch(void* const* d_in, const int* in_sizes, int n_in,
                              void* d_out, int out_size, void* d_ws, size_t ws_size,
                              hipStream_t stream) {
    const float* pred = (const float*)d_in[0];
    const float* bias = (const float*)d_in[1];
    float*       out  = (float*)d_out;

    const int blocks = B * NCG * NSEG;   // 1024
    smoother_kernel<<<blocks, 512, 0, stream>>>(pred, bias, out);
}